// Round 8
// baseline (135.405 us; speedup 1.0000x reference)
//
#include <hip/hip_runtime.h>
#include <math.h>

#define HW 16384
#define C_DIM 256
#define V_DIM 6
#define PT 64
#define BK 32
#define KROW 34   // 68 B row stride = 17 words, coprime with 32 banks:
                  // uint2 writes 4/bank (floor), b128 reads 8/bank (floor)

typedef short bf16x8 __attribute__((ext_vector_type(8)));
typedef float f32x4 __attribute__((ext_vector_type(4)));

// Barrier that does NOT drain vmcnt (T4): hipcc's __syncthreads() emits
// s_waitcnt vmcnt(0) lgkmcnt(0) before s_barrier, killing any global-load
// prefetch pipeline. We only need lgkmcnt(0) (our ds_writes visible to the
// other waves); vm prefetches are wave-private and compiler-counted.
#define SYNC_KEEP_VM()                                          \
    do {                                                        \
        asm volatile("s_waitcnt lgkmcnt(0)" ::: "memory");      \
        __builtin_amdgcn_sched_barrier(0);                      \
        __builtin_amdgcn_s_barrier();                           \
        __builtin_amdgcn_sched_barrier(0);                      \
    } while (0)

// fp32 -> bf16 hi/lo split (truncation). |x - (hi+lo)| <= 2^-16 |x|.
__device__ __forceinline__ void split2(float x, unsigned short& h,
                                       unsigned short& l) {
    unsigned u = __float_as_uint(x);
    h = (unsigned short)(u >> 16);
    float xl = x - __uint_as_float(u & 0xFFFF0000u);
    l = (unsigned short)(__float_as_uint(xl) >> 16);
}

// ---------------------------------------------------------------------------
// K1: M = Wq^T @ Wk, stored as bf16 hi/lo.
// ---------------------------------------------------------------------------
__global__ void compute_M_kernel(const float* __restrict__ Wq,
                                 const float* __restrict__ Wk,
                                 unsigned short* __restrict__ Mh,
                                 unsigned short* __restrict__ Ml) {
    const int i = blockIdx.x;
    const int j = threadIdx.x;
    float a0 = 0.f, a1 = 0.f, a2 = 0.f, a3 = 0.f;
    #pragma unroll 4
    for (int o = 0; o < C_DIM; o += 4) {
        a0 = fmaf(Wq[(o + 0) * C_DIM + i], Wk[(o + 0) * C_DIM + j], a0);
        a1 = fmaf(Wq[(o + 1) * C_DIM + i], Wk[(o + 1) * C_DIM + j], a1);
        a2 = fmaf(Wq[(o + 2) * C_DIM + i], Wk[(o + 2) * C_DIM + j], a2);
        a3 = fmaf(Wq[(o + 3) * C_DIM + i], Wk[(o + 3) * C_DIM + j], a3);
    }
    float acc = (a0 + a1) + (a2 + a3);
    unsigned short h, l;
    split2(acc, h, l);
    Mh[i * C_DIM + j] = h;
    Ml[i * C_DIM + j] = l;
}

// ---------------------------------------------------------------------------
// K2 v8: score[v][p] = q[v,:,p]^T M k[v,:,p], 3-term split-bf16 MFMA.
// Same structure as v7 (512 thr, 8 waves, wave owns 32 i-rows, k depth-2
// prefetch, A depth-1 pipeline, dbuf LDS, 1 barrier/ks) BUT the barrier is
// SYNC_KEEP_VM, so the prefetches actually survive across iterations, and
// KROW=34 removes the 8-way ds_write bank conflict.
// ---------------------------------------------------------------------------
__global__ __launch_bounds__(512, 4) void score_kernel(
        const float* __restrict__ q, const float* __restrict__ k,
        const unsigned short* __restrict__ Mh,
        const unsigned short* __restrict__ Ml,
        float* __restrict__ score) {
    const int tid  = threadIdx.x;
    const int lane = tid & 63;          // also the staging pixel
    const int w    = tid >> 6;          // wave 0..7; also staging ch-group
    const int pt   = blockIdx.x & 255;
    const int v    = blockIdx.x >> 8;
    const int gp0  = pt * PT;
    const int l15  = lane & 15;
    const int l4   = lane >> 4;

    __shared__ __align__(16) unsigned short Kh_s[2][PT * KROW];
    __shared__ __align__(16) unsigned short Kl_s[2][PT * KROW];
    __shared__ float s_red[8][PT];

    const float* kv = k + (size_t)v * C_DIM * HW + gp0;
    const float* qv = q + (size_t)v * C_DIM * HW + gp0;
    const int ibase = w * 32;

    f32x4 acc[2][4];
    #pragma unroll
    for (int a = 0; a < 2; ++a)
        #pragma unroll
        for (int b = 0; b < 4; ++b)
            acc[a][b] = (f32x4){0.f, 0.f, 0.f, 0.f};

    float kx[2][4];              // k prefetch, depth 2 (tile t in kx[t&1])
    bf16x8 Ah[2][2], Al[2][2];   // A pipeline, depth 1 (tile t in set t&1)

    // ---- prologue ----
    {
        const float* kp = kv + (size_t)(w * 4) * HW + lane;
        float x[4];
        #pragma unroll
        for (int e = 0; e < 4; ++e) x[e] = kp[(size_t)e * HW];
        unsigned short h[4], l[4];
        #pragma unroll
        for (int e = 0; e < 4; ++e) split2(x[e], h[e], l[e]);
        uint2 H, L;
        H.x = (unsigned)h[0] | ((unsigned)h[1] << 16);
        H.y = (unsigned)h[2] | ((unsigned)h[3] << 16);
        L.x = (unsigned)l[0] | ((unsigned)l[1] << 16);
        L.y = (unsigned)l[2] | ((unsigned)l[3] << 16);
        *(uint2*)&Kh_s[0][lane * KROW + w * 4] = H;
        *(uint2*)&Kl_s[0][lane * KROW + w * 4] = L;

        const float* kp1 = kv + (size_t)(BK + w * 4) * HW + lane;
        #pragma unroll
        for (int e = 0; e < 4; ++e) kx[1][e] = kp1[(size_t)e * HW];

        #pragma unroll
        for (int it = 0; it < 2; ++it) {
            int row = ibase + it * 16 + l15;
            Ah[0][it] = *(const bf16x8*)(Mh + (size_t)row * C_DIM + l4 * 8);
            Al[0][it] = *(const bf16x8*)(Ml + (size_t)row * C_DIM + l4 * 8);
        }
    }
    SYNC_KEEP_VM();

    #pragma unroll
    for (int ks = 0; ks < 8; ++ks) {
        const int cur = ks & 1;

        // (1) A(ks+1) (L2) ...
        if (ks < 7) {
            #pragma unroll
            for (int it = 0; it < 2; ++it) {
                int row = ibase + it * 16 + l15;
                Ah[cur ^ 1][it] = *(const bf16x8*)(Mh + (size_t)row * C_DIM +
                                                   (ks + 1) * BK + l4 * 8);
                Al[cur ^ 1][it] = *(const bf16x8*)(Ml + (size_t)row * C_DIM +
                                                   (ks + 1) * BK + l4 * 8);
            }
        }
        // (2) ... then k(ks+2) (HBM) into the set tile ks vacated
        if (ks < 6) {
            const float* kp = kv + (size_t)((ks + 2) * BK + w * 4) * HW + lane;
            #pragma unroll
            for (int e = 0; e < 4; ++e) kx[cur][e] = kp[(size_t)e * HW];
        }

        // (3) B fragments from LDS + MFMAs (A loaded last iteration)
        bf16x8 Bh[4];
        #pragma unroll
        for (int jt = 0; jt < 4; ++jt) {
            int bp = jt * 16 + l15;
            Bh[jt] = *(const bf16x8*)&Kh_s[cur][bp * KROW + l4 * 8];
        }
        #pragma unroll
        for (int it = 0; it < 2; ++it)
            #pragma unroll
            for (int jt = 0; jt < 4; ++jt)
                acc[it][jt] = __builtin_amdgcn_mfma_f32_16x16x32_bf16(
                                  Ah[cur][it], Bh[jt], acc[it][jt], 0, 0, 0);
        #pragma unroll
        for (int it = 0; it < 2; ++it)
            #pragma unroll
            for (int jt = 0; jt < 4; ++jt)
                acc[it][jt] = __builtin_amdgcn_mfma_f32_16x16x32_bf16(
                                  Al[cur][it], Bh[jt], acc[it][jt], 0, 0, 0);
        bf16x8 Bl[4];
        #pragma unroll
        for (int jt = 0; jt < 4; ++jt) {
            int bp = jt * 16 + l15;
            Bl[jt] = *(const bf16x8*)&Kl_s[cur][bp * KROW + l4 * 8];
        }
        #pragma unroll
        for (int it = 0; it < 2; ++it)
            #pragma unroll
            for (int jt = 0; jt < 4; ++jt)
                acc[it][jt] = __builtin_amdgcn_mfma_f32_16x16x32_bf16(
                                  Ah[cur][it], Bl[jt], acc[it][jt], 0, 0, 0);

        // (4) split tile ks+1 (regs loaded at iter ks-1) and write the LDS
        //     buffer the MFMAs just vacated
        if (ks < 7) {
            unsigned short h[4], l[4];
            #pragma unroll
            for (int e = 0; e < 4; ++e) split2(kx[cur ^ 1][e], h[e], l[e]);
            uint2 H, L;
            H.x = (unsigned)h[0] | ((unsigned)h[1] << 16);
            H.y = (unsigned)h[2] | ((unsigned)h[3] << 16);
            L.x = (unsigned)l[0] | ((unsigned)l[1] << 16);
            L.y = (unsigned)l[2] | ((unsigned)l[3] << 16);
            *(uint2*)&Kh_s[cur ^ 1][lane * KROW + w * 4] = H;
            *(uint2*)&Kl_s[cur ^ 1][lane * KROW + w * 4] = L;
        }
        SYNC_KEEP_VM();
    }

    // ---- epilogue: sp[p] = sum_i q[i,p] * T[i,p] over this wave's 32 rows ----
    float sp[4];
    #pragma unroll
    for (int jt = 0; jt < 4; ++jt) sp[jt] = 0.f;
    #pragma unroll
    for (int jt = 0; jt < 4; ++jt) {
        #pragma unroll
        for (int it = 0; it < 2; ++it) {
            int irow = ibase + it * 16 + l4 * 4;
            const float* qp = qv + (size_t)irow * HW + jt * 16 + l15;
            #pragma unroll
            for (int r = 0; r < 4; ++r)
                sp[jt] = fmaf(qp[(size_t)r * HW], acc[it][jt][r], sp[jt]);
        }
        sp[jt] += __shfl_xor(sp[jt], 16, 64);
        sp[jt] += __shfl_xor(sp[jt], 32, 64);
    }
    if (lane < 16) {
        #pragma unroll
        for (int jt = 0; jt < 4; ++jt)
            s_red[w][jt * 16 + lane] = sp[jt];
    }
    __syncthreads();
    if (tid < PT) {
        float s = 0.f;
        #pragma unroll
        for (int ww = 0; ww < 8; ++ww) s += s_red[ww][tid];
        score[v * HW + gp0 + tid] = s;
    }
}

// ---------------------------------------------------------------------------
// K3: in-place softmax over views.
// ---------------------------------------------------------------------------
__global__ __launch_bounds__(256) void softmax_w_kernel(float* __restrict__ score) {
    const int p = blockIdx.x * 256 + threadIdx.x;
    float s[V_DIM];
    float mx = -1e30f;
    #pragma unroll
    for (int vv = 0; vv < V_DIM; ++vv) {
        s[vv] = score[vv * HW + p];
        mx = fmaxf(mx, s[vv]);
    }
    float sum = 0.f;
    #pragma unroll
    for (int vv = 0; vv < V_DIM; ++vv) {
        s[vv] = __expf(s[vv] - mx);
        sum += s[vv];
    }
    float inv = 1.0f / sum;
    #pragma unroll
    for (int vv = 0; vv < V_DIM; ++vv)
        score[vv * HW + p] = s[vv] * inv;
}

// ---------------------------------------------------------------------------
// K4: split Wv into bf16 hi/lo (reuses the Mh/Ml workspace).
// ---------------------------------------------------------------------------
__global__ void wsplit_kernel(const float* __restrict__ Wv,
                              unsigned short* __restrict__ Wvh,
                              unsigned short* __restrict__ Wvl) {
    const int i = blockIdx.x;
    const int j = threadIdx.x;
    unsigned short h, l;
    split2(Wv[i * C_DIM + j], h, l);
    Wvh[i * C_DIM + j] = h;
    Wvl[i * C_DIM + j] = l;
}

// ---------------------------------------------------------------------------
// K5 v8: out = Wv @ vbar.  Same fixes: SYNC_KEEP_VM barrier, KROW=34, and
// v-prefetch deepened to 2 tiles (24 HBM loads/iter were depth-1).
// ---------------------------------------------------------------------------
__global__ __launch_bounds__(512, 2) void out_gemm_kernel(
        const float* __restrict__ vin,
        const unsigned short* __restrict__ Wvh,
        const unsigned short* __restrict__ Wvl,
        const float* __restrict__ wsm,
        float* __restrict__ out) {
    const int tid  = threadIdx.x;
    const int lane = tid & 63;
    const int w    = tid >> 6;          // 0..7
    const int gp0  = blockIdx.x * PT;
    const int l15  = lane & 15;
    const int l4   = lane >> 4;
    const int jg   = w;                 // staging channel group (4 ch)

    __shared__ __align__(16) unsigned short Xh_s[2][PT * KROW];
    __shared__ __align__(16) unsigned short Xl_s[2][PT * KROW];

    float wr[V_DIM];
    #pragma unroll
    for (int vv = 0; vv < V_DIM; ++vv) wr[vv] = wsm[vv * HW + gp0 + lane];

    const float* vbase = vin + gp0 + lane;
    const int obase = w * 32;

    f32x4 acc[2][4];
    #pragma unroll
    for (int a = 0; a < 2; ++a)
        #pragma unroll
        for (int b = 0; b < 4; ++b)
            acc[a][b] = (f32x4){0.f, 0.f, 0.f, 0.f};

    float vx[2][4][V_DIM];       // v prefetch, depth 2 (tile t in vx[t&1])
    bf16x8 Ah[2][2], Al[2][2];   // Wv pipeline, depth 1

    // ---- prologue ----
    {
        // tile 0: load, weighted-sum, split, write buf 0
        float x0[4][V_DIM];
        #pragma unroll
        for (int vv = 0; vv < V_DIM; ++vv)
            #pragma unroll
            for (int e = 0; e < 4; ++e)
                x0[e][vv] = vbase[(size_t)(vv * C_DIM + jg * 4 + e) * HW];
        unsigned short h[4], l[4];
        #pragma unroll
        for (int e = 0; e < 4; ++e) {
            float s = 0.f;
            #pragma unroll
            for (int vv = 0; vv < V_DIM; ++vv) s = fmaf(wr[vv], x0[e][vv], s);
            split2(s, h[e], l[e]);
        }
        uint2 H, L;
        H.x = (unsigned)h[0] | ((unsigned)h[1] << 16);
        H.y = (unsigned)h[2] | ((unsigned)h[3] << 16);
        L.x = (unsigned)l[0] | ((unsigned)l[1] << 16);
        L.y = (unsigned)l[2] | ((unsigned)l[3] << 16);
        *(uint2*)&Xh_s[0][lane * KROW + jg * 4] = H;
        *(uint2*)&Xl_s[0][lane * KROW + jg * 4] = L;

        // tile 1 raw values -> vx[1]
        #pragma unroll
        for (int vv = 0; vv < V_DIM; ++vv)
            #pragma unroll
            for (int e = 0; e < 4; ++e)
                vx[1][e][vv] = vbase[(size_t)(vv * C_DIM + BK + jg * 4 + e) * HW];

        // Wv(0) -> set 0
        #pragma unroll
        for (int it = 0; it < 2; ++it) {
            int row = obase + it * 16 + l15;
            Ah[0][it] = *(const bf16x8*)(Wvh + (size_t)row * C_DIM + l4 * 8);
            Al[0][it] = *(const bf16x8*)(Wvl + (size_t)row * C_DIM + l4 * 8);
        }
    }
    SYNC_KEEP_VM();

    #pragma unroll
    for (int ks = 0; ks < 8; ++ks) {
        const int cur = ks & 1;

        // (1) Wv(ks+1) fragments (L2)
        if (ks < 7) {
            #pragma unroll
            for (int it = 0; it < 2; ++it) {
                int row = obase + it * 16 + l15;
                Ah[cur ^ 1][it] = *(const bf16x8*)(Wvh + (size_t)row * C_DIM +
                                                   (ks + 1) * BK + l4 * 8);
                Al[cur ^ 1][it] = *(const bf16x8*)(Wvl + (size_t)row * C_DIM +
                                                   (ks + 1) * BK + l4 * 8);
            }
        }
        // (2) v(ks+2) raw loads (HBM, deep)
        if (ks < 6) {
            #pragma unroll
            for (int vv = 0; vv < V_DIM; ++vv)
                #pragma unroll
                for (int e = 0; e < 4; ++e)
                    vx[cur][e][vv] = vbase[(size_t)(vv * C_DIM + (ks + 2) * BK +
                                                    jg * 4 + e) * HW];
        }

        // (3) B fragments from LDS + MFMAs
        bf16x8 Bh[4], Bl[4];
        #pragma unroll
        for (int jt = 0; jt < 4; ++jt) {
            int bp = jt * 16 + l15;
            Bh[jt] = *(const bf16x8*)&Xh_s[cur][bp * KROW + l4 * 8];
            Bl[jt] = *(const bf16x8*)&Xl_s[cur][bp * KROW + l4 * 8];
        }
        #pragma unroll
        for (int it = 0; it < 2; ++it)
            #pragma unroll
            for (int jt = 0; jt < 4; ++jt)
                acc[it][jt] = __builtin_amdgcn_mfma_f32_16x16x32_bf16(
                                  Ah[cur][it], Bh[jt], acc[it][jt], 0, 0, 0);
        #pragma unroll
        for (int it = 0; it < 2; ++it)
            #pragma unroll
            for (int jt = 0; jt < 4; ++jt)
                acc[it][jt] = __builtin_amdgcn_mfma_f32_16x16x32_bf16(
                                  Ah[cur][it], Bl[jt], acc[it][jt], 0, 0, 0);
        #pragma unroll
        for (int it = 0; it < 2; ++it)
            #pragma unroll
            for (int jt = 0; jt < 4; ++jt)
                acc[it][jt] = __builtin_amdgcn_mfma_f32_16x16x32_bf16(
                                  Al[cur][it], Bh[jt], acc[it][jt], 0, 0, 0);

        // (4) weighted-sum + split tile ks+1 (regs from iter ks-1), write
        if (ks < 7) {
            unsigned short h[4], l[4];
            #pragma unroll
            for (int e = 0; e < 4; ++e) {
                float s = 0.f;
                #pragma unroll
                for (int vv = 0; vv < V_DIM; ++vv)
                    s = fmaf(wr[vv], vx[cur ^ 1][e][vv], s);
                split2(s, h[e], l[e]);
            }
            uint2 H, L;
            H.x = (unsigned)h[0] | ((unsigned)h[1] << 16);
            H.y = (unsigned)h[2] | ((unsigned)h[3] << 16);
            L.x = (unsigned)l[0] | ((unsigned)l[1] << 16);
            L.y = (unsigned)l[2] | ((unsigned)l[3] << 16);
            *(uint2*)&Xh_s[cur ^ 1][lane * KROW + jg * 4] = H;
            *(uint2*)&Xl_s[cur ^ 1][lane * KROW + jg * 4] = L;
        }
        SYNC_KEEP_VM();
    }

    // ---- store D tile ----
    #pragma unroll
    for (int it = 0; it < 2; ++it)
        #pragma unroll
        for (int jt = 0; jt < 4; ++jt)
            #pragma unroll
            for (int r = 0; r < 4; ++r) {
                int o = obase + it * 16 + l4 * 4 + r;
                out[(size_t)o * HW + gp0 + jt * 16 + l15] = acc[it][jt][r];
            }
}

// ---------------------------------------------------------------------------
extern "C" void kernel_launch(void* const* d_in, const int* in_sizes, int n_in,
                              void* d_out, int out_size, void* d_ws, size_t ws_size,
                              hipStream_t stream) {
    const float* q  = (const float*)d_in[0];
    const float* k  = (const float*)d_in[1];
    const float* v  = (const float*)d_in[2];
    const float* Wq = (const float*)d_in[3];
    const float* Wk = (const float*)d_in[4];
    const float* Wv = (const float*)d_in[5];
    float* out = (float*)d_out;

    unsigned short* Mh = (unsigned short*)d_ws;          // 128 KB (later: Wvh)
    unsigned short* Ml = Mh + C_DIM * C_DIM;             // 128 KB (later: Wvl)
    float* score = (float*)(Ml + C_DIM * C_DIM);         // 384 KB (-> weights)

    compute_M_kernel<<<C_DIM, C_DIM, 0, stream>>>(Wq, Wk, Mh, Ml);
    score_kernel<<<V_DIM * 256, 512, 0, stream>>>(q, k, Mh, Ml, score);
    softmax_w_kernel<<<HW / 256, 256, 0, stream>>>(score);
    wsplit_kernel<<<C_DIM, C_DIM, 0, stream>>>(Wv, Mh, Ml);
    out_gemm_kernel<<<HW / PT, 512, 0, stream>>>(v, Mh, Ml, score, out);
}

// Round 9
// 121.428 us; speedup vs baseline: 1.1151x; 1.1151x over previous
//
#include <hip/hip_runtime.h>
#include <math.h>

#define HW 16384
#define C_DIM 256
#define V_DIM 6
#define PT 64
#define BK 32
#define KROW 40   // 80 B row = 20 words: b128 reads hit the 8/bank floor

typedef short bf16x8 __attribute__((ext_vector_type(8)));
typedef float f32x4 __attribute__((ext_vector_type(4)));

// fp32 -> bf16 hi/lo split (truncation). |x - (hi+lo)| <= 2^-16 |x|.
__device__ __forceinline__ void split2(float x, unsigned short& h,
                                       unsigned short& l) {
    unsigned u = __float_as_uint(x);
    h = (unsigned short)(u >> 16);
    float xl = x - __uint_as_float(u & 0xFFFF0000u);
    l = (unsigned short)(__float_as_uint(xl) >> 16);
}

// ---------------------------------------------------------------------------
// K1: M = Wq^T @ Wk, stored as bf16 hi/lo.
// ---------------------------------------------------------------------------
__global__ void compute_M_kernel(const float* __restrict__ Wq,
                                 const float* __restrict__ Wk,
                                 unsigned short* __restrict__ Mh,
                                 unsigned short* __restrict__ Ml) {
    const int i = blockIdx.x;
    const int j = threadIdx.x;
    float a0 = 0.f, a1 = 0.f, a2 = 0.f, a3 = 0.f;
    #pragma unroll 4
    for (int o = 0; o < C_DIM; o += 4) {
        a0 = fmaf(Wq[(o + 0) * C_DIM + i], Wk[(o + 0) * C_DIM + j], a0);
        a1 = fmaf(Wq[(o + 1) * C_DIM + i], Wk[(o + 1) * C_DIM + j], a1);
        a2 = fmaf(Wq[(o + 2) * C_DIM + i], Wk[(o + 2) * C_DIM + j], a2);
        a3 = fmaf(Wq[(o + 3) * C_DIM + i], Wk[(o + 3) * C_DIM + j], a3);
    }
    float acc = (a0 + a1) + (a2 + a3);
    unsigned short h, l;
    split2(acc, h, l);
    Mh[i * C_DIM + j] = h;
    Ml[i * C_DIM + j] = l;
}

// ---------------------------------------------------------------------------
// K2 v9 (base = r7, best measured): 512 thr = 8 waves; wave owns 32 i-rows.
// Changes vs r7:
//   * k-prefetch depth 3 (kx[3]): split of k(ks+1) uses regs loaded TWO
//     iterations ago (~1400cy cover > ~900cy HBM latency).
//   * q-tile prefetched into 32 registers at iter ks=7 (no other prefetch
//     issues there) and the ks=7 end-of-loop barrier is dropped, so the
//     epilogue dot runs on registers instead of a serial cold-HBM chain.
// Plain __syncthreads (r8's asm barrier regressed), KROW=40 (34 regressed).
// ---------------------------------------------------------------------------
__global__ __launch_bounds__(512, 3) void score_kernel(
        const float* __restrict__ q, const float* __restrict__ k,
        const unsigned short* __restrict__ Mh,
        const unsigned short* __restrict__ Ml,
        float* __restrict__ score) {
    const int tid  = threadIdx.x;
    const int lane = tid & 63;          // also the staging pixel
    const int w    = tid >> 6;          // wave 0..7; also staging ch-group
    const int pt   = blockIdx.x & 255;
    const int v    = blockIdx.x >> 8;
    const int gp0  = pt * PT;
    const int l15  = lane & 15;
    const int l4   = lane >> 4;

    __shared__ __align__(16) unsigned short Kh_s[2][PT * KROW];
    __shared__ __align__(16) unsigned short Kl_s[2][PT * KROW];
    __shared__ float s_red[8][PT];

    const float* kv = k + (size_t)v * C_DIM * HW + gp0;
    const float* qv = q + (size_t)v * C_DIM * HW + gp0;
    const int ibase = w * 32;

    f32x4 acc[2][4];
    #pragma unroll
    for (int a = 0; a < 2; ++a)
        #pragma unroll
        for (int b = 0; b < 4; ++b)
            acc[a][b] = (f32x4){0.f, 0.f, 0.f, 0.f};

    float kx[3][4];              // k prefetch, depth 3 (tile t in kx[t%3])
    bf16x8 Ah[2][2], Al[2][2];   // A pipeline, depth 1 (tile t in set t&1)
    float qx[32];                // q epilogue prefetch (filled at ks==7)

    // ---- prologue: stage k(0) -> LDS buf0; k(1),k(2) -> regs; A(0) ----
    {
        const float* kp = kv + (size_t)(w * 4) * HW + lane;
        float x[4];
        #pragma unroll
        for (int e = 0; e < 4; ++e) x[e] = kp[(size_t)e * HW];
        unsigned short h[4], l[4];
        #pragma unroll
        for (int e = 0; e < 4; ++e) split2(x[e], h[e], l[e]);
        uint2 H, L;
        H.x = (unsigned)h[0] | ((unsigned)h[1] << 16);
        H.y = (unsigned)h[2] | ((unsigned)h[3] << 16);
        L.x = (unsigned)l[0] | ((unsigned)l[1] << 16);
        L.y = (unsigned)l[2] | ((unsigned)l[3] << 16);
        *(uint2*)&Kh_s[0][lane * KROW + w * 4] = H;
        *(uint2*)&Kl_s[0][lane * KROW + w * 4] = L;

        const float* kp1 = kv + (size_t)(1 * BK + w * 4) * HW + lane;
        #pragma unroll
        for (int e = 0; e < 4; ++e) kx[1][e] = kp1[(size_t)e * HW];
        const float* kp2 = kv + (size_t)(2 * BK + w * 4) * HW + lane;
        #pragma unroll
        for (int e = 0; e < 4; ++e) kx[2][e] = kp2[(size_t)e * HW];

        #pragma unroll
        for (int it = 0; it < 2; ++it) {
            int row = ibase + it * 16 + l15;
            Ah[0][it] = *(const bf16x8*)(Mh + (size_t)row * C_DIM + l4 * 8);
            Al[0][it] = *(const bf16x8*)(Ml + (size_t)row * C_DIM + l4 * 8);
        }
    }
    __syncthreads();

    #pragma unroll
    for (int ks = 0; ks < 8; ++ks) {
        const int cur = ks & 1;

        // (1) A(ks+1) (L2) ...
        if (ks < 7) {
            #pragma unroll
            for (int it = 0; it < 2; ++it) {
                int row = ibase + it * 16 + l15;
                Ah[cur ^ 1][it] = *(const bf16x8*)(Mh + (size_t)row * C_DIM +
                                                   (ks + 1) * BK + l4 * 8);
                Al[cur ^ 1][it] = *(const bf16x8*)(Ml + (size_t)row * C_DIM +
                                                   (ks + 1) * BK + l4 * 8);
            }
        }
        // (2) ... then k(ks+3) (HBM, depth-3)
        if (ks < 5) {
            const float* kp = kv + (size_t)((ks + 3) * BK + w * 4) * HW + lane;
            #pragma unroll
            for (int e = 0; e < 4; ++e) kx[ks % 3][e] = kp[(size_t)e * HW];
        }
        // (2b) last iteration: issue the epilogue q-tile loads instead
        if (ks == 7) {
            #pragma unroll
            for (int jt = 0; jt < 4; ++jt)
                #pragma unroll
                for (int it = 0; it < 2; ++it) {
                    int irow = ibase + it * 16 + l4 * 4;
                    const float* qp = qv + (size_t)irow * HW + jt * 16 + l15;
                    #pragma unroll
                    for (int r = 0; r < 4; ++r)
                        qx[jt * 8 + it * 4 + r] = qp[(size_t)r * HW];
                }
        }

        // (3) B fragments from LDS + MFMAs (A loaded last iteration)
        bf16x8 Bh[4];
        #pragma unroll
        for (int jt = 0; jt < 4; ++jt) {
            int bp = jt * 16 + l15;
            Bh[jt] = *(const bf16x8*)&Kh_s[cur][bp * KROW + l4 * 8];
        }
        #pragma unroll
        for (int it = 0; it < 2; ++it)
            #pragma unroll
            for (int jt = 0; jt < 4; ++jt)
                acc[it][jt] = __builtin_amdgcn_mfma_f32_16x16x32_bf16(
                                  Ah[cur][it], Bh[jt], acc[it][jt], 0, 0, 0);
        #pragma unroll
        for (int it = 0; it < 2; ++it)
            #pragma unroll
            for (int jt = 0; jt < 4; ++jt)
                acc[it][jt] = __builtin_amdgcn_mfma_f32_16x16x32_bf16(
                                  Al[cur][it], Bh[jt], acc[it][jt], 0, 0, 0);
        bf16x8 Bl[4];
        #pragma unroll
        for (int jt = 0; jt < 4; ++jt) {
            int bp = jt * 16 + l15;
            Bl[jt] = *(const bf16x8*)&Kl_s[cur][bp * KROW + l4 * 8];
        }
        #pragma unroll
        for (int it = 0; it < 2; ++it)
            #pragma unroll
            for (int jt = 0; jt < 4; ++jt)
                acc[it][jt] = __builtin_amdgcn_mfma_f32_16x16x32_bf16(
                                  Ah[cur][it], Bl[jt], acc[it][jt], 0, 0, 0);

        // (4) split tile ks+1 (regs loaded TWO iterations ago) and write the
        //     LDS buffer the MFMAs just vacated
        if (ks < 7) {
            unsigned short h[4], l[4];
            #pragma unroll
            for (int e = 0; e < 4; ++e) split2(kx[(ks + 1) % 3][e], h[e], l[e]);
            uint2 H, L;
            H.x = (unsigned)h[0] | ((unsigned)h[1] << 16);
            H.y = (unsigned)h[2] | ((unsigned)h[3] << 16);
            L.x = (unsigned)l[0] | ((unsigned)l[1] << 16);
            L.y = (unsigned)l[2] | ((unsigned)l[3] << 16);
            *(uint2*)&Kh_s[cur ^ 1][lane * KROW + w * 4] = H;
            *(uint2*)&Kl_s[cur ^ 1][lane * KROW + w * 4] = L;
            __syncthreads();    // no barrier after the final iteration
        }
    }

    // ---- epilogue: sp[p] = sum_i q[i,p]*T[i,p], q from registers ----
    float sp[4];
    #pragma unroll
    for (int jt = 0; jt < 4; ++jt) sp[jt] = 0.f;
    #pragma unroll
    for (int jt = 0; jt < 4; ++jt) {
        #pragma unroll
        for (int it = 0; it < 2; ++it)
            #pragma unroll
            for (int r = 0; r < 4; ++r)
                sp[jt] = fmaf(qx[jt * 8 + it * 4 + r], acc[it][jt][r], sp[jt]);
        sp[jt] += __shfl_xor(sp[jt], 16, 64);
        sp[jt] += __shfl_xor(sp[jt], 32, 64);
    }
    if (lane < 16) {
        #pragma unroll
        for (int jt = 0; jt < 4; ++jt)
            s_red[w][jt * 16 + lane] = sp[jt];
    }
    __syncthreads();
    if (tid < PT) {
        float s = 0.f;
        #pragma unroll
        for (int ww = 0; ww < 8; ++ww) s += s_red[ww][tid];
        score[v * HW + gp0 + tid] = s;
    }
}

// ---------------------------------------------------------------------------
// K4: split Wv into bf16 hi/lo (reuses the Mh/Ml workspace).
// ---------------------------------------------------------------------------
__global__ void wsplit_kernel(const float* __restrict__ Wv,
                              unsigned short* __restrict__ Wvh,
                              unsigned short* __restrict__ Wvl) {
    const int i = blockIdx.x;
    const int j = threadIdx.x;
    unsigned short h, l;
    split2(Wv[i * C_DIM + j], h, l);
    Wvh[i * C_DIM + j] = h;
    Wvl[i * C_DIM + j] = l;
}

// ---------------------------------------------------------------------------
// K5 v9: out = Wv @ vbar.  r7 structure (plain barriers, KROW=40) +
// depth-2 v-prefetch + INLINE per-pixel softmax (softmax_w kernel removed:
// reads raw scores, 6 loads + ~15 VALU per lane).
// ---------------------------------------------------------------------------
__global__ __launch_bounds__(512, 2) void out_gemm_kernel(
        const float* __restrict__ vin,
        const unsigned short* __restrict__ Wvh,
        const unsigned short* __restrict__ Wvl,
        const float* __restrict__ score,
        float* __restrict__ out) {
    const int tid  = threadIdx.x;
    const int lane = tid & 63;
    const int w    = tid >> 6;          // 0..7
    const int gp0  = blockIdx.x * PT;
    const int l15  = lane & 15;
    const int l4   = lane >> 4;
    const int jg   = w;                 // staging channel group (4 ch)

    __shared__ __align__(16) unsigned short Xh_s[2][PT * KROW];
    __shared__ __align__(16) unsigned short Xl_s[2][PT * KROW];

    // inline softmax over views for this lane's pixel
    float wr[V_DIM];
    {
        float s[V_DIM];
        float mx = -1e30f;
        #pragma unroll
        for (int vv = 0; vv < V_DIM; ++vv) {
            s[vv] = score[vv * HW + gp0 + lane];
            mx = fmaxf(mx, s[vv]);
        }
        float sum = 0.f;
        #pragma unroll
        for (int vv = 0; vv < V_DIM; ++vv) {
            s[vv] = __expf(s[vv] - mx);
            sum += s[vv];
        }
        float inv = 1.0f / sum;
        #pragma unroll
        for (int vv = 0; vv < V_DIM; ++vv) wr[vv] = s[vv] * inv;
    }

    const float* vbase = vin + gp0 + lane;
    const int obase = w * 32;

    f32x4 acc[2][4];
    #pragma unroll
    for (int a = 0; a < 2; ++a)
        #pragma unroll
        for (int b = 0; b < 4; ++b)
            acc[a][b] = (f32x4){0.f, 0.f, 0.f, 0.f};

    float vx[2][4][V_DIM];       // v prefetch, depth 2 (tile t in vx[t&1])
    bf16x8 Ah[2][2], Al[2][2];   // Wv pipeline, depth 1

    // ---- prologue ----
    {
        float x0[4][V_DIM];
        #pragma unroll
        for (int vv = 0; vv < V_DIM; ++vv)
            #pragma unroll
            for (int e = 0; e < 4; ++e)
                x0[e][vv] = vbase[(size_t)(vv * C_DIM + jg * 4 + e) * HW];
        unsigned short h[4], l[4];
        #pragma unroll
        for (int e = 0; e < 4; ++e) {
            float s = 0.f;
            #pragma unroll
            for (int vv = 0; vv < V_DIM; ++vv) s = fmaf(wr[vv], x0[e][vv], s);
            split2(s, h[e], l[e]);
        }
        uint2 H, L;
        H.x = (unsigned)h[0] | ((unsigned)h[1] << 16);
        H.y = (unsigned)h[2] | ((unsigned)h[3] << 16);
        L.x = (unsigned)l[0] | ((unsigned)l[1] << 16);
        L.y = (unsigned)l[2] | ((unsigned)l[3] << 16);
        *(uint2*)&Xh_s[0][lane * KROW + jg * 4] = H;
        *(uint2*)&Xl_s[0][lane * KROW + jg * 4] = L;

        #pragma unroll
        for (int vv = 0; vv < V_DIM; ++vv)
            #pragma unroll
            for (int e = 0; e < 4; ++e)
                vx[1][e][vv] = vbase[(size_t)(vv * C_DIM + BK + jg * 4 + e) * HW];

        #pragma unroll
        for (int it = 0; it < 2; ++it) {
            int row = obase + it * 16 + l15;
            Ah[0][it] = *(const bf16x8*)(Wvh + (size_t)row * C_DIM + l4 * 8);
            Al[0][it] = *(const bf16x8*)(Wvl + (size_t)row * C_DIM + l4 * 8);
        }
    }
    __syncthreads();

    #pragma unroll
    for (int ks = 0; ks < 8; ++ks) {
        const int cur = ks & 1;

        // (1) Wv(ks+1) fragments (L2)
        if (ks < 7) {
            #pragma unroll
            for (int it = 0; it < 2; ++it) {
                int row = obase + it * 16 + l15;
                Ah[cur ^ 1][it] = *(const bf16x8*)(Wvh + (size_t)row * C_DIM +
                                                   (ks + 1) * BK + l4 * 8);
                Al[cur ^ 1][it] = *(const bf16x8*)(Wvl + (size_t)row * C_DIM +
                                                   (ks + 1) * BK + l4 * 8);
            }
        }
        // (2) v(ks+2) raw loads (HBM)
        if (ks < 6) {
            #pragma unroll
            for (int vv = 0; vv < V_DIM; ++vv)
                #pragma unroll
                for (int e = 0; e < 4; ++e)
                    vx[cur][e][vv] = vbase[(size_t)(vv * C_DIM + (ks + 2) * BK +
                                                    jg * 4 + e) * HW];
        }

        // (3) B fragments from LDS + MFMAs
        bf16x8 Bh[4], Bl[4];
        #pragma unroll
        for (int jt = 0; jt < 4; ++jt) {
            int bp = jt * 16 + l15;
            Bh[jt] = *(const bf16x8*)&Xh_s[cur][bp * KROW + l4 * 8];
            Bl[jt] = *(const bf16x8*)&Xl_s[cur][bp * KROW + l4 * 8];
        }
        #pragma unroll
        for (int it = 0; it < 2; ++it)
            #pragma unroll
            for (int jt = 0; jt < 4; ++jt)
                acc[it][jt] = __builtin_amdgcn_mfma_f32_16x16x32_bf16(
                                  Ah[cur][it], Bh[jt], acc[it][jt], 0, 0, 0);
        #pragma unroll
        for (int it = 0; it < 2; ++it)
            #pragma unroll
            for (int jt = 0; jt < 4; ++jt)
                acc[it][jt] = __builtin_amdgcn_mfma_f32_16x16x32_bf16(
                                  Ah[cur][it], Bl[jt], acc[it][jt], 0, 0, 0);
        #pragma unroll
        for (int it = 0; it < 2; ++it)
            #pragma unroll
            for (int jt = 0; jt < 4; ++jt)
                acc[it][jt] = __builtin_amdgcn_mfma_f32_16x16x32_bf16(
                                  Al[cur][it], Bh[jt], acc[it][jt], 0, 0, 0);

        // (4) weighted-sum + split tile ks+1 (regs from iter ks-1), write
        if (ks < 7) {
            unsigned short h[4], l[4];
            #pragma unroll
            for (int e = 0; e < 4; ++e) {
                float s = 0.f;
                #pragma unroll
                for (int vv = 0; vv < V_DIM; ++vv)
                    s = fmaf(wr[vv], vx[cur ^ 1][e][vv], s);
                split2(s, h[e], l[e]);
            }
            uint2 H, L;
            H.x = (unsigned)h[0] | ((unsigned)h[1] << 16);
            H.y = (unsigned)h[2] | ((unsigned)h[3] << 16);
            L.x = (unsigned)l[0] | ((unsigned)l[1] << 16);
            L.y = (unsigned)l[2] | ((unsigned)l[3] << 16);
            *(uint2*)&Xh_s[cur ^ 1][lane * KROW + jg * 4] = H;
            *(uint2*)&Xl_s[cur ^ 1][lane * KROW + jg * 4] = L;
        }
        __syncthreads();
    }

    // ---- store D tile ----
    #pragma unroll
    for (int it = 0; it < 2; ++it)
        #pragma unroll
        for (int jt = 0; jt < 4; ++jt)
            #pragma unroll
            for (int r = 0; r < 4; ++r) {
                int o = obase + it * 16 + l4 * 4 + r;
                out[(size_t)o * HW + gp0 + jt * 16 + l15] = acc[it][jt][r];
            }
}

// ---------------------------------------------------------------------------
extern "C" void kernel_launch(void* const* d_in, const int* in_sizes, int n_in,
                              void* d_out, int out_size, void* d_ws, size_t ws_size,
                              hipStream_t stream) {
    const float* q  = (const float*)d_in[0];
    const float* k  = (const float*)d_in[1];
    const float* v  = (const float*)d_in[2];
    const float* Wq = (const float*)d_in[3];
    const float* Wk = (const float*)d_in[4];
    const float* Wv = (const float*)d_in[5];
    float* out = (float*)d_out;

    unsigned short* Mh = (unsigned short*)d_ws;          // 128 KB (later: Wvh)
    unsigned short* Ml = Mh + C_DIM * C_DIM;             // 128 KB (later: Wvl)
    float* score = (float*)(Ml + C_DIM * C_DIM);         // 384 KB

    compute_M_kernel<<<C_DIM, C_DIM, 0, stream>>>(Wq, Wk, Mh, Ml);
    score_kernel<<<V_DIM * 256, 512, 0, stream>>>(q, k, Mh, Ml, score);
    wsplit_kernel<<<C_DIM, C_DIM, 0, stream>>>(Wv, Mh, Ml);
    out_gemm_kernel<<<HW / PT, 512, 0, stream>>>(v, Mh, Ml, score, out);
}